// Round 1
// baseline (109.970 us; speedup 1.0000x reference)
//
#include <hip/hip_runtime.h>
#include <hip/hip_bf16.h>

// NT-Xent loss, N=4096, D=256, fp32 inputs, fp32 scalar output.
// loss = mean_i [ log( sum_{j != i} exp(2*cos(zn_i, zn_j)) ) - 2*cos(zn_i, zn_pair(i)) ]
//
// k1: normalize rows -> bf16 zn in ws, fp32 inv-norms, zero rowsum
// k2: Gram-matrix row-wise sum of exp via 16x16x32 bf16 MFMA (flash-style)
//     v2: 64 rows/wave (B-frag feeds 4 MFMAs), global_load_lds DMA staging with
//     XOR-swizzled source (rule #21), 256-thr blocks x grid 512 = 2 blocks/CU.
// k3: per-row contrib = log(rowsum - exp(diag)) - pair_sim   (fp32-exact pair term)
// k4: reduce 8192 contribs -> d_out[0]

#define NROWS 8192
#define NHALF 4096
#define DDIM  256

typedef __bf16 bf16;
typedef __bf16 bf16x4 __attribute__((ext_vector_type(4)));
typedef __bf16 bf16x8 __attribute__((ext_vector_type(8)));
typedef float  f32x4  __attribute__((ext_vector_type(4)));

__constant__ const float kTwoLog2e = 2.8853900817779268f;  // 2*log2(e): exp(2x)=exp2(kTwoLog2e*x)
__constant__ const float kLn2      = 0.6931471805599453f;

__device__ __forceinline__ const float* zrow(const float* z1, const float* z2, int r) {
  return (r < NHALF) ? (z1 + (size_t)r * DDIM) : (z2 + (size_t)(r - NHALF) * DDIM);
}

// ---------------- k1: normalize ----------------
__global__ void k_normalize(const float* __restrict__ z1, const float* __restrict__ z2,
                            bf16* __restrict__ zn, float* __restrict__ invn,
                            float* __restrict__ rowsum) {
  const int wave = threadIdx.x >> 6, lane = threadIdx.x & 63;
  const int row = blockIdx.x * 4 + wave;
  const float* src = zrow(z1, z2, row);
  f32x4 v = *(const f32x4*)(src + lane * 4);
  float ss = v.x * v.x + v.y * v.y + v.z * v.z + v.w * v.w;
#pragma unroll
  for (int off = 1; off < 64; off <<= 1) ss += __shfl_xor(ss, off);
  const float inv = 1.0f / fmaxf(sqrtf(ss), 1e-8f);
  bf16x4 o;
  o.x = (bf16)(v.x * inv); o.y = (bf16)(v.y * inv);
  o.z = (bf16)(v.z * inv); o.w = (bf16)(v.w * inv);
  *(bf16x4*)(zn + (size_t)row * DDIM + lane * 4) = o;
  if (lane == 0) { invn[row] = inv; rowsum[row] = 0.0f; }
}

// ---------------- k2: Gram row-sums of exp ----------------
// 256 threads = 4 waves. Block tile: BMG=256 rows (64/wave, A in regs) x K=256.
// Col loop: BNG=32 cols staged in LDS via global_load_lds DMA (16B), double-buffered.
// LDS layout: col-row r (0..31) x 32 chunks of 16B, chunk q stored at slot q ^ (r&7)
// (T2 swizzle; DMA writes linearly, so the GLOBAL source is pre-swizzled).
#define BMG 256
#define BNG 32
#define CSPLIT 16

typedef const __attribute__((address_space(1))) unsigned int* as1_u32p;
typedef __attribute__((address_space(3))) unsigned int* as3_u32p;

__device__ __forceinline__ void load_lds16(const void* g, void* l) {
  __builtin_amdgcn_global_load_lds((as1_u32p)g, (as3_u32p)l, 16, 0, 0);
}

__global__ __launch_bounds__(256, 2) void k_gram(const bf16* __restrict__ zn,
                                                 float* __restrict__ rowsum) {
  __shared__ __align__(16) unsigned char ldsb[2][BNG * 512];
  const int tid  = threadIdx.x;
  const int wave = tid >> 6, lane = tid & 63;
  const int quad = lane >> 4, l15 = lane & 15;
  const int rowblk = blockIdx.x >> 4, csplit = blockIdx.x & 15;
  const int c0 = csplit * (NROWS / CSPLIT);   // 512-col slab per block
  const int iters = (NROWS / CSPLIT) / BNG;   // 16

  // --- issue DMA for tile 0 first (overlaps with A-fragment loads) ---
  {
    const unsigned char* src0 = (const unsigned char*)(zn + (size_t)c0 * DDIM);
#pragma unroll
    for (int j = 0; j < 4; ++j) {
      const int p = (wave * 4 + j) * 64 + lane;          // chunk position 0..1023
      const int r = p >> 5;                               // staged col-row 0..31
      const int q = (p & 31) ^ (r & 7);                   // source chunk (swizzle inverse)
      load_lds16(src0 + r * 512 + q * 16, &ldsb[0][(wave * 4 + j) * 1024]);
    }
  }

  // --- A fragments: wave owns rows R0 + s*16 + l15 (s=0..3); chunk = kk*4 + quad ---
  const int R0 = rowblk * BMG + wave * 64;
  bf16x8 a[4][8];
#pragma unroll
  for (int s = 0; s < 4; ++s) {
    const bf16x8* ap = (const bf16x8*)(zn + (size_t)(R0 + s * 16 + l15) * DDIM);
#pragma unroll
    for (int kk = 0; kk < 8; ++kk) a[s][kk] = ap[kk * 4 + quad];
  }

  float sum[4][4];
#pragma unroll
  for (int s = 0; s < 4; ++s)
#pragma unroll
    for (int r = 0; r < 4; ++r) sum[s][r] = 0.0f;

  const f32x4 zero4 = {0.f, 0.f, 0.f, 0.f};

  for (int it = 0; it < iters; ++it) {
    __syncthreads();  // vmcnt(0)+barrier: buf[it&1] DMA complete, prior reads of buf[it&1^1] done
    const unsigned char* bp = ldsb[it & 1];

    if (it + 1 < iters) {  // prefetch next tile into the other buffer (drains at next barrier)
      const unsigned char* srcn =
          (const unsigned char*)(zn + (size_t)(c0 + (it + 1) * BNG) * DDIM);
#pragma unroll
      for (int j = 0; j < 4; ++j) {
        const int p = (wave * 4 + j) * 64 + lane;
        const int r = p >> 5;
        const int q = (p & 31) ^ (r & 7);
        load_lds16(srcn + r * 512 + q * 16, &ldsb[(it + 1) & 1][(wave * 4 + j) * 1024]);
      }
    }

    f32x4 acc[4][2];
#pragma unroll
    for (int s = 0; s < 4; ++s) { acc[s][0] = zero4; acc[s][1] = zero4; }

#pragma unroll
    for (int kk = 0; kk < 8; ++kk) {
      bf16x8 b[2];
#pragma unroll
      for (int cs = 0; cs < 2; ++cs) {
        const int rb = cs * 16 + l15;                    // staged col-row
        const int q  = (kk * 4 + quad) ^ (rb & 7);       // swizzled chunk slot
        b[cs] = *(const bf16x8*)(bp + rb * 512 + q * 16);
      }
#pragma unroll
      for (int s = 0; s < 4; ++s)
#pragma unroll
        for (int cs = 0; cs < 2; ++cs)
          acc[s][cs] =
              __builtin_amdgcn_mfma_f32_16x16x32_bf16(a[s][kk], b[cs], acc[s][cs], 0, 0, 0);
    }

#pragma unroll
    for (int s = 0; s < 4; ++s)
#pragma unroll
      for (int r = 0; r < 4; ++r)
        sum[s][r] += __builtin_amdgcn_exp2f(acc[s][0][r] * kTwoLog2e) +
                     __builtin_amdgcn_exp2f(acc[s][1][r] * kTwoLog2e);
  }

  // C/D layout (m89-verified): element (row = quad*4 + r, col = l15). Reduce cols over quad's 16 lanes.
#pragma unroll
  for (int s = 0; s < 4; ++s)
#pragma unroll
    for (int r = 0; r < 4; ++r) {
      float v = sum[s][r];
      v += __shfl_xor(v, 1); v += __shfl_xor(v, 2);
      v += __shfl_xor(v, 4); v += __shfl_xor(v, 8);
      if (l15 == 0)
        atomicAdd(&rowsum[R0 + s * 16 + quad * 4 + r], v);  // 16 col-split adders per row
    }
}

// ---------------- k3: per-row contribution ----------------
__global__ void k_finalize(const float* __restrict__ z1, const float* __restrict__ z2,
                           const bf16* __restrict__ zn, const float* __restrict__ invn,
                           const float* __restrict__ rowsum, float* __restrict__ contrib) {
  const int wave = threadIdx.x >> 6, lane = threadIdx.x & 63;
  const int row = blockIdx.x * 4 + wave;
  const int pr = (row < NHALF) ? row + NHALF : row - NHALF;

  f32x4 a4 = *(const f32x4*)(zrow(z1, z2, row) + lane * 4);
  f32x4 b4 = *(const f32x4*)(zrow(z1, z2, pr) + lane * 4);
  bf16x4 nb = *(const bf16x4*)(zn + (size_t)row * DDIM + lane * 4);

  float pd = a4.x * b4.x + a4.y * b4.y + a4.z * b4.z + a4.w * b4.w;
  float f0 = (float)nb.x, f1 = (float)nb.y, f2 = (float)nb.z, f3 = (float)nb.w;
  float nd = f0 * f0 + f1 * f1 + f2 * f2 + f3 * f3;
#pragma unroll
  for (int off = 1; off < 64; off <<= 1) {
    pd += __shfl_xor(pd, off);
    nd += __shfl_xor(nd, off);
  }
  if (lane == 0) {
    const float p = 2.0f * pd * invn[row] * invn[pr];               // exact fp32 pair sim
    const float dexp = __builtin_amdgcn_exp2f(kTwoLog2e * nd);      // the GEMM's diagonal term
    const float lse = __builtin_amdgcn_logf(rowsum[row] - dexp) * kLn2;
    contrib[row] = lse - p;
  }
}

// ---------------- k4: reduce 8192 contribs ----------------
__global__ void k_reduce(const float* __restrict__ contrib, float* __restrict__ out) {
  const int wave = threadIdx.x >> 6, lane = threadIdx.x & 63;
  float acc = 0.0f;
  for (int i = threadIdx.x; i < NROWS; i += 256) acc += contrib[i];
#pragma unroll
  for (int off = 1; off < 64; off <<= 1) acc += __shfl_xor(acc, off);
  __shared__ float wsum[4];
  if (lane == 0) wsum[wave] = acc;
  __syncthreads();
  if (threadIdx.x == 0)
    out[0] = (wsum[0] + wsum[1] + wsum[2] + wsum[3]) * (1.0f / (float)NROWS);
}

extern "C" void kernel_launch(void* const* d_in, const int* in_sizes, int n_in,
                              void* d_out, int out_size, void* d_ws, size_t ws_size,
                              hipStream_t stream) {
  const float* z1 = (const float*)d_in[0];
  const float* z2 = (const float*)d_in[1];
  unsigned char* ws = (unsigned char*)d_ws;

  // ws layout: zn bf16 [8192*256] (4 MB) | invn f32[8192] | rowsum f32[8192] | contrib f32[8192]
  bf16* zn = (bf16*)ws;
  float* invn = (float*)(ws + (size_t)NROWS * DDIM * sizeof(bf16));
  float* rowsum = invn + NROWS;
  float* contrib = rowsum + NROWS;

  hipLaunchKernelGGL(k_normalize, dim3(NROWS / 4), dim3(256), 0, stream, z1, z2, zn, invn, rowsum);
  hipLaunchKernelGGL(k_gram, dim3((NROWS / BMG) * CSPLIT), dim3(256), 0, stream, zn, rowsum);
  hipLaunchKernelGGL(k_finalize, dim3(NROWS / 4), dim3(256), 0, stream, z1, z2, zn, invn, rowsum,
                     contrib);
  hipLaunchKernelGGL(k_reduce, dim3(1), dim3(256), 0, stream, contrib, (float*)d_out);
}